// Round 8
// baseline (123.292 us; speedup 1.0000x reference)
//
#include <hip/hip_runtime.h>

#define PS 32
#define NPIX (PS * PS)
#define NB 36
#define WPB 4       // waves (patches) per block
#define HCOL 64     // one exclusive histogram column per lane
#define HWORDS (NB * HCOL)   // 2304 words per wave

// ---------------------------------------------------------------------------
// Init kernel: gk10[p] = float32(10 * CircularGaussKernel(32)) computed in f64,
// replicating numpy linspace + exp + normalize semantics, then cast to f32.
// ---------------------------------------------------------------------------
__global__ __launch_bounds__(256) void gk_init_kernel(float* __restrict__ gk10) {
    __shared__ double red[256];
    const int tid = threadIdx.x;
    const double delta = 32.0 / 31.0;       // numpy linspace step, f64
    const double sigma2 = 0.9 * 256.0;      // 0.9 * half^2, f64

    double kv[4];
    double s = 0.0;
#pragma unroll
    for (int j = 0; j < 4; ++j) {
        int p = tid * 4 + j;
        int r = p >> 5, c = p & 31;
        double xr = (r == 31) ? 16.0 : ((double)r * delta + (-16.0));
        double xc = (c == 31) ? 16.0 : ((double)c * delta + (-16.0));
        double d2 = xc * xc + xr * xr;
        kv[j] = exp(-d2 / sigma2);
        s += kv[j];
    }
    red[tid] = s;
    __syncthreads();
    for (int off = 128; off > 0; off >>= 1) {
        if (tid < off) red[tid] += red[tid + off];
        __syncthreads();
    }
    double sum = red[0];
#pragma unroll
    for (int j = 0; j < 4; ++j) {
        int p = tid * 4 + j;
        gk10[p] = __fmul_rn(10.0f, (float)(kv[j] / sum));
    }
}

// ---------------------------------------------------------------------------
// Cold path: exact f64 recompute of one flagged bin-boundary pixel.
// Adds into the lane's exclusive histogram column (plain RMW, race-free).
// ---------------------------------------------------------------------------
__device__ __attribute__((noinline))
void fix_pixel(float lv, float rv, float uv, float dv, float gk, float* col) {
    const float PI_F    = 3.14159265358979323846f;
    const float TWOPI_F = 6.28318530717958647692f;
    float gx = __fmul_rn(0.5f, __fsub_rn(lv, rv));
    float gy = __fmul_rn(0.5f, __fsub_rn(uv, dv));
    float s2 = __fadd_rn(__fadd_rn(__fmul_rn(gx, gx), __fmul_rn(gy, gy)), 1e-10f);
    float mag = __fmul_rn(__fsqrt_rn(s2), gk);

    float ori  = (float)atan2((double)gy, (double)gx);  // correctly-rounded f32
    float obig = __fdiv_rn(__fmul_rn(36.0f, __fadd_rn(ori, PI_F)), TWOPI_F);
    float bo0f = floorf(obig);
    float wo1  = __fsub_rn(obig, bo0f);
    int bo = (int)bo0f;
    if (bo >= NB) bo -= NB;
    float wo0 = __fmul_rn(__fsub_rn(1.0f, wo1), mag);
    col[bo * HCOL] += wo0;
}

// ---------------------------------------------------------------------------
// Main kernel: ONE WAVE PER PATCH, zero LDS atomics, NO LDS tile.
// Lane layout: 8x8 grid of 4x4 pixel subtiles held in registers; halo
// exchange via 16 lane shuffles. LDS holds only the per-wave histogram
// ([36][64], lane-exclusive columns, bank = l%32 -> free 2-way).
// ---------------------------------------------------------------------------
__global__ __launch_bounds__(256) void orient_kernel(const float* __restrict__ x,
                                                     const float* __restrict__ gk10,
                                                     float* __restrict__ out) {
    const float PI_F    = 3.14159265358979323846f;   // 0x40490FDB
    const float TWOPI_F = 6.28318530717958647692f;   // 0x40C90FDB

    __shared__ __align__(16) float hist[WPB][HWORDS];

    const int tid = threadIdx.x;
    const int w = tid >> 6;          // wave id within block
    const int l = tid & 63;          // lane within wave
    const int patch = blockIdx.x * WPB + w;

    float* hw = hist[w];

    const int sr = l >> 3;           // subtile row 0..7
    const int sc = l & 7;            // subtile col 0..7

    // ---- Global loads: lane's 4x4 subtile + matching gaussian weights
    const float* xb = x + (size_t)patch * NPIX + (sr * 4) * PS + sc * 4;
    const float* gb = gk10 + (sr * 4) * PS + sc * 4;
    float4 sq[4], gq[4];
#pragma unroll
    for (int k = 0; k < 4; ++k) {
        sq[k] = *reinterpret_cast<const float4*>(xb + k * PS);
        gq[k] = *reinterpret_cast<const float4*>(gb + k * PS);
    }

    // ---- Zero hist region while loads are in flight (2304 words = 9 q/lane)
    {
        float4 z4 = make_float4(0.0f, 0.0f, 0.0f, 0.0f);
        float4* hz = reinterpret_cast<float4*>(hw);
#pragma unroll
        for (int p = 0; p < 9; ++p) hz[p * 64 + l] = z4;
    }

    // Unpack to scalar arrays (register file)
    float s[4][4], g[4][4];
#pragma unroll
    for (int k = 0; k < 4; ++k) {
        s[k][0] = sq[k].x; s[k][1] = sq[k].y; s[k][2] = sq[k].z; s[k][3] = sq[k].w;
        g[k][0] = gq[k].x; g[k][1] = gq[k].y; g[k][2] = gq[k].z; g[k][3] = gq[k].w;
    }

    // ---- Halo exchange via lane shuffles (16 bpermutes)
    const int upL = (sr > 0) ? (l - 8) : l;
    const int dnL = (sr < 7) ? (l + 8) : l;
    const int lfL = (sc > 0) ? (l - 1) : l;
    const int rtL = (sc < 7) ? (l + 1) : l;
    float Uh[4], Dh[4], Lh[4], Rh[4];
#pragma unroll
    for (int j = 0; j < 4; ++j) {
        Uh[j] = __shfl(s[3][j], upL, 64);   // lane above's bottom row
        Dh[j] = __shfl(s[0][j], dnL, 64);   // lane below's top row
    }
#pragma unroll
    for (int k = 0; k < 4; ++k) {
        Lh[k] = __shfl(s[k][3], lfL, 64);   // left lane's col 3
        Rh[k] = __shfl(s[k][0], rtL, 64);   // right lane's col 0
    }
    // Replicate padding at patch borders
    if (sr == 0) {
#pragma unroll
        for (int j = 0; j < 4; ++j) Uh[j] = s[0][j];
    }
    if (sr == 7) {
#pragma unroll
        for (int j = 0; j < 4; ++j) Dh[j] = s[3][j];
    }
    if (sc == 0) {
#pragma unroll
        for (int k = 0; k < 4; ++k) Lh[k] = s[k][0];
    }
    if (sc == 7) {
#pragma unroll
        for (int k = 0; k < 4; ++k) Rh[k] = s[k][3];
    }

    // ---- Hot loop: 16 pixels, all operands in registers; hist via
    // lane-exclusive-column RMW (bitwise-identical to round 7).
    unsigned int badbits = 0;
    float* mycol = hw + l;
#pragma unroll
    for (int k = 0; k < 4; ++k) {
#pragma unroll
        for (int j = 0; j < 4; ++j) {
            float lv = (j == 0) ? Lh[k] : s[k][j - 1];
            float rv = (j == 3) ? Rh[k] : s[k][j + 1];
            float uv = (k == 0) ? Uh[j] : s[k - 1][j];
            float dv = (k == 3) ? Dh[j] : s[k + 1][j];

            // Reference f32 op order for magnitude (no contraction):
            float gx = __fmul_rn(0.5f, __fsub_rn(lv, rv));
            float gy = __fmul_rn(0.5f, __fsub_rn(uv, dv));
            float s2 = __fadd_rn(__fadd_rn(__fmul_rn(gx, gx), __fmul_rn(gy, gy)), 1e-10f);
            float mag = __fmul_rn(__fsqrt_rn(s2), g[k][j]);

            // Fast atan2 directly in bin units: obig = (atan2+pi)*36/(2pi)
            float ax = fabsf(gx), ay = fabsf(gy);
            float mn = fminf(ax, ay), mx = fmaxf(ax, ay);
            float rr = mn * __builtin_amdgcn_rcpf(mx);   // ~1 ulp
            rr = (mx > 0.0f) ? rr : 0.0f;                // atan2(0,0) = 0
            float t  = rr * rr;
            float u = 0.00282363896258175373077393f;     // SLEEF deg-17 odd minimax
            u = fmaf(u, t, -0.0159569028764963150024414f);
            u = fmaf(u, t,  0.0425049886107444763183594f);
            u = fmaf(u, t, -0.0748900920152664184570312f);
            u = fmaf(u, t,  0.106347933411598205566406f);
            u = fmaf(u, t, -0.142027363181114196777344f);
            u = fmaf(u, t,  0.199926957488059997558594f);
            u = fmaf(u, t, -0.333331018686294555664062f);
            float at = fmaf(rr * t, u, rr);              // atan(rr), [0, pi/4]

            // Quadrant folding to bin units (exact-integer offsets)
            bool c1 = ay > ax;
            bool c2 = gx < 0.0f;
            bool c3 = gy < 0.0f;
            float S  = c1 ? -1.0f : 1.0f;
            float Cb = c1 ? 27.0f : 18.0f;
            S  = c2 ? -S : S;
            Cb = c2 ? __fsub_rn(54.0f, Cb) : Cb;
            S  = c3 ? -S : S;
            Cb = c3 ? __fsub_rn(36.0f, Cb) : Cb;
            float obig = fmaf(at * S, 5.72957795130823208768f, Cb);  // [0,36]
            float bo0f = floorf(obig);
            float wo1  = __fsub_rn(obig, bo0f);

            bool bad = (wo1 < 2e-5f) | (wo1 > 1.0f - 2e-5f);
            if (!bad) {
                int bo = (int)bo0f;
                if (bo >= NB) bo -= NB;
                float wo0 = __fmul_rn(__fsub_rn(1.0f, wo1), mag);
                mycol[bo * HCOL] += wo0;     // plain LDS RMW, lane-exclusive
            } else {
                badbits |= (1u << (k * 4 + j));
            }
        }
    }

    // ---- Rare exact f64 fixup (ballot-guarded; operands from live registers)
    if (__ballot(badbits != 0)) {
#pragma unroll
        for (int k = 0; k < 4; ++k) {
#pragma unroll
            for (int j = 0; j < 4; ++j) {
                if (badbits & (1u << (k * 4 + j))) {
                    float lv = (j == 0) ? Lh[k] : s[k][j - 1];
                    float rv = (j == 3) ? Rh[k] : s[k][j + 1];
                    float uv = (k == 0) ? Uh[j] : s[k - 1][j];
                    float dv = (k == 3) ? Dh[j] : s[k + 1][j];
                    fix_pixel(lv, rv, uv, dv, g[k][j], mycol);
                }
            }
        }
    }
    asm volatile("s_waitcnt lgkmcnt(0)" ::: "memory");

    // ---- Reduction: lane b (<36) sums its 64-word row via rotated b64 reads
    // (bank phase = 2*(b+k) % 32 -> 16 phases over 36 lanes ~= free 2-way)
    float hval = 0.0f;
    if (l < NB) {
        const float2* row2 = reinterpret_cast<const float2*>(hw + l * HCOL);
        float tot = 0.0f;
#pragma unroll
        for (int k = 0; k < 32; ++k) {
            float2 a = row2[(k + l) & 31];
            tot += (a.x + a.y);
        }
        hval = __fmul_rn(tot, 1.0f / 1024.0f);   // exact power-of-2 scale
    }

    // ---- Smoothing via lane shuffles (zero pad; lane 36 holds 0)
    float hm = __shfl_up(hval, 1, 64);
    if (l == 0) hm = 0.0f;
    float hp = __shfl_down(hval, 1, 64);
    float sm = 0.0f;
    if (l < NB) {
        sm = __fadd_rn(__fadd_rn(__fmul_rn(0.33f, hm), __fmul_rn(0.34f, hval)),
                       __fmul_rn(0.33f, hp));
    }

    // ---- First-wins argmax via packed-key butterfly (sm >= 0 always)
    unsigned long long key =
        (l < NB) ? ((((unsigned long long)__float_as_uint(sm)) << 6) |
                    (unsigned long long)(63 - l))
                 : 0ull;
#pragma unroll
    for (int off = 32; off > 0; off >>= 1) {
        unsigned long long o = __shfl_xor(key, off, 64);
        key = (o > key) ? o : key;
    }

    if (l == 0) {
        int bi = 63 - (int)(key & 63);
        float t2 = __fdiv_rn(__fmul_rn(TWOPI_F, (float)bi), 36.0f);
        out[patch] = __fsub_rn(PI_F, t2);
    }
}

extern "C" void kernel_launch(void* const* d_in, const int* in_sizes, int n_in,
                              void* d_out, int out_size, void* d_ws, size_t ws_size,
                              hipStream_t stream) {
    const float* x = (const float*)d_in[0];
    float* out = (float*)d_out;
    float* gk10 = (float*)d_ws;   // 1024 floats = 4 KB scratch

    const int B = in_sizes[0] / NPIX;

    gk_init_kernel<<<1, 256, 0, stream>>>(gk10);
    orient_kernel<<<B / WPB, 256, 0, stream>>>(x, gk10, out);
}

// Round 9
// 112.461 us; speedup vs baseline: 1.0963x; 1.0963x over previous
//
#include <hip/hip_runtime.h>

#define PS 32
#define NPIX (PS * PS)
#define NB 36
#define WPB 4       // waves (patches) per block
#define HCOL 64     // one exclusive histogram column per lane
#define HWORDS (NB * HCOL)   // 2304 words per wave

// ---------------------------------------------------------------------------
// Init kernel: gk10[p] = float32(10 * CircularGaussKernel(32)) computed in f64,
// replicating numpy linspace + exp + normalize semantics, then cast to f32.
// ---------------------------------------------------------------------------
__global__ __launch_bounds__(256) void gk_init_kernel(float* __restrict__ gk10) {
    __shared__ double red[256];
    const int tid = threadIdx.x;
    const double delta = 32.0 / 31.0;       // numpy linspace step, f64
    const double sigma2 = 0.9 * 256.0;      // 0.9 * half^2, f64

    double kv[4];
    double s = 0.0;
#pragma unroll
    for (int j = 0; j < 4; ++j) {
        int p = tid * 4 + j;
        int r = p >> 5, c = p & 31;
        double xr = (r == 31) ? 16.0 : ((double)r * delta + (-16.0));
        double xc = (c == 31) ? 16.0 : ((double)c * delta + (-16.0));
        double d2 = xc * xc + xr * xr;
        kv[j] = exp(-d2 / sigma2);
        s += kv[j];
    }
    red[tid] = s;
    __syncthreads();
    for (int off = 128; off > 0; off >>= 1) {
        if (tid < off) red[tid] += red[tid + off];
        __syncthreads();
    }
    double sum = red[0];
#pragma unroll
    for (int j = 0; j < 4; ++j) {
        int p = tid * 4 + j;
        gk10[p] = __fmul_rn(10.0f, (float)(kv[j] / sum));
    }
}

// ---------------------------------------------------------------------------
// Cold path: exact f64 recompute of one flagged bin-boundary pixel.
// Adds into the lane's exclusive histogram column (plain RMW, race-free).
// ---------------------------------------------------------------------------
__device__ __attribute__((noinline))
void fix_pixel(float lv, float rv, float uv, float dv, float gk, float* col) {
    const float PI_F    = 3.14159265358979323846f;
    const float TWOPI_F = 6.28318530717958647692f;
    float gx = __fmul_rn(0.5f, __fsub_rn(lv, rv));
    float gy = __fmul_rn(0.5f, __fsub_rn(uv, dv));
    float s2 = __fadd_rn(__fadd_rn(__fmul_rn(gx, gx), __fmul_rn(gy, gy)), 1e-10f);
    float mag = __fmul_rn(__fsqrt_rn(s2), gk);

    float ori  = (float)atan2((double)gy, (double)gx);  // correctly-rounded f32
    float obig = __fdiv_rn(__fmul_rn(36.0f, __fadd_rn(ori, PI_F)), TWOPI_F);
    float bo0f = floorf(obig);
    float wo1  = __fsub_rn(obig, bo0f);
    int bo = (int)bo0f;
    if (bo >= NB) bo -= NB;
    float wo0 = __fmul_rn(__fsub_rn(1.0f, wo1), mag);
    col[bo * HCOL] += wo0;
}

// ---------------------------------------------------------------------------
// Main kernel: ONE WAVE PER PATCH, zero LDS atomics, no LDS tile, and a
// BRANCH-FREE hot loop (flagged pixels add 0.0f to their own column - no-op).
// Lane layout: 8x8 grid of 4x4 pixel subtiles in registers; halos via shfl.
// ---------------------------------------------------------------------------
__global__ __launch_bounds__(256) void orient_kernel(const float* __restrict__ x,
                                                     const float* __restrict__ gk10,
                                                     float* __restrict__ out) {
    const float PI_F    = 3.14159265358979323846f;   // 0x40490FDB
    const float TWOPI_F = 6.28318530717958647692f;   // 0x40C90FDB

    __shared__ __align__(16) float hist[WPB][HWORDS];

    const int tid = threadIdx.x;
    const int w = tid >> 6;          // wave id within block
    const int l = tid & 63;          // lane within wave
    const int patch = blockIdx.x * WPB + w;

    float* hw = hist[w];

    const int sr = l >> 3;           // subtile row 0..7
    const int sc = l & 7;            // subtile col 0..7

    // ---- Global loads: lane's 4x4 subtile + matching gaussian weights
    const float* xb = x + (size_t)patch * NPIX + (sr * 4) * PS + sc * 4;
    const float* gb = gk10 + (sr * 4) * PS + sc * 4;
    float4 sq[4], gq[4];
#pragma unroll
    for (int k = 0; k < 4; ++k) {
        sq[k] = *reinterpret_cast<const float4*>(xb + k * PS);
        gq[k] = *reinterpret_cast<const float4*>(gb + k * PS);
    }

    // ---- Zero hist region while loads are in flight (2304 words = 9 q/lane)
    {
        float4 z4 = make_float4(0.0f, 0.0f, 0.0f, 0.0f);
        float4* hz = reinterpret_cast<float4*>(hw);
#pragma unroll
        for (int p = 0; p < 9; ++p) hz[p * 64 + l] = z4;
    }

    // Unpack to scalar arrays (register file)
    float s[4][4], g[4][4];
#pragma unroll
    for (int k = 0; k < 4; ++k) {
        s[k][0] = sq[k].x; s[k][1] = sq[k].y; s[k][2] = sq[k].z; s[k][3] = sq[k].w;
        g[k][0] = gq[k].x; g[k][1] = gq[k].y; g[k][2] = gq[k].z; g[k][3] = gq[k].w;
    }

    // ---- Halo exchange via lane shuffles; border replicate via cndmask
    const int upL = (sr > 0) ? (l - 8) : l;
    const int dnL = (sr < 7) ? (l + 8) : l;
    const int lfL = (sc > 0) ? (l - 1) : l;
    const int rtL = (sc < 7) ? (l + 1) : l;
    float Uh[4], Dh[4], Lh[4], Rh[4];
#pragma unroll
    for (int j = 0; j < 4; ++j) {
        float tu = __shfl(s[3][j], upL, 64);   // lane above's bottom row
        float td = __shfl(s[0][j], dnL, 64);   // lane below's top row
        Uh[j] = (sr == 0) ? s[0][j] : tu;
        Dh[j] = (sr == 7) ? s[3][j] : td;
    }
#pragma unroll
    for (int k = 0; k < 4; ++k) {
        float tl = __shfl(s[k][3], lfL, 64);   // left lane's col 3
        float tr = __shfl(s[k][0], rtL, 64);   // right lane's col 0
        Lh[k] = (sc == 0) ? s[k][0] : tl;
        Rh[k] = (sc == 7) ? s[k][3] : tr;
    }

    // ---- Branch-free hot loop: 16 pixels, all operands in registers
    unsigned int badbits = 0;
    float* mycol = hw + l;
#pragma unroll
    for (int k = 0; k < 4; ++k) {
#pragma unroll
        for (int j = 0; j < 4; ++j) {
            float lv = (j == 0) ? Lh[k] : s[k][j - 1];
            float rv = (j == 3) ? Rh[k] : s[k][j + 1];
            float uv = (k == 0) ? Uh[j] : s[k - 1][j];
            float dv = (k == 3) ? Dh[j] : s[k + 1][j];

            // Reference f32 op order for magnitude (no contraction):
            float gx = __fmul_rn(0.5f, __fsub_rn(lv, rv));
            float gy = __fmul_rn(0.5f, __fsub_rn(uv, dv));
            float s2 = __fadd_rn(__fadd_rn(__fmul_rn(gx, gx), __fmul_rn(gy, gy)), 1e-10f);
            float mag = __fmul_rn(__fsqrt_rn(s2), g[k][j]);

            // Fast atan -> bin units. FLT_MIN clamp kills the 0/0 case
            // (rr bits unchanged for any normal mx).
            float ax = fabsf(gx), ay = fabsf(gy);
            float mn = fminf(ax, ay);
            float mx = fmaxf(fmaxf(ax, ay), 1.17549435e-38f);
            float rr = mn * __builtin_amdgcn_rcpf(mx);   // ~1 ulp
            float t  = rr * rr;
            float u = 0.00282363896258175373077393f;     // SLEEF deg-17 odd minimax
            u = fmaf(u, t, -0.0159569028764963150024414f);
            u = fmaf(u, t,  0.0425049886107444763183594f);
            u = fmaf(u, t, -0.0748900920152664184570312f);
            u = fmaf(u, t,  0.106347933411598205566406f);
            u = fmaf(u, t, -0.142027363181114196777344f);
            u = fmaf(u, t,  0.199926957488059997558594f);
            u = fmaf(u, t, -0.333331018686294555664062f);
            float at  = fmaf(rr * t, u, rr);             // atan(rr), [0, pi/4]
            float atb = at * 5.72957795130823208768f;    // bins, [0, 4.5]

            // Quadrant fold: a9 -> a18 -> copysign -> +18  (gx,gy never -0.0)
            float a9  = (ay > ax)    ? __fsub_rn(9.0f,  atb) : atb;
            float a18 = (gx < 0.0f)  ? __fsub_rn(18.0f, a9)  : a9;
            float as  = copysignf(a18, gy);              // v_bfi_b32
            float obig = __fadd_rn(as, 18.0f);           // [0, 36]
            float bo0f = floorf(obig);
            float wo1  = __fsub_rn(obig, bo0f);

            // One-cmp boundary test: wo1 within ~2e-5 of an integer
            bool bad = fabsf(__fsub_rn(wo1, 0.5f)) >= 0.49998f;

            float wo0 = __fmul_rn(__fsub_rn(1.0f, wo1), mag);
            wo0 = bad ? 0.0f : wo0;                      // flagged: add 0 (no-op)
            int bo = (int)fminf(bo0f, 35.0f);            // unflagged => bo<=35
            mycol[bo * HCOL] += wo0;                     // plain LDS RMW, exclusive

            badbits |= bad ? (1u << (k * 4 + j)) : 0u;
        }
    }

    // ---- Rare exact f64 fixup (ballot-guarded; operands from live registers)
    if (__ballot(badbits != 0)) {
#pragma unroll
        for (int k = 0; k < 4; ++k) {
#pragma unroll
            for (int j = 0; j < 4; ++j) {
                if (badbits & (1u << (k * 4 + j))) {
                    float lv = (j == 0) ? Lh[k] : s[k][j - 1];
                    float rv = (j == 3) ? Rh[k] : s[k][j + 1];
                    float uv = (k == 0) ? Uh[j] : s[k - 1][j];
                    float dv = (k == 3) ? Dh[j] : s[k + 1][j];
                    fix_pixel(lv, rv, uv, dv, g[k][j], mycol);
                }
            }
        }
    }
    asm volatile("s_waitcnt lgkmcnt(0)" ::: "memory");

    // ---- Reduction: lane b (<36) sums its 64-word row via rotated b64 reads
    float hval = 0.0f;
    if (l < NB) {
        const float2* row2 = reinterpret_cast<const float2*>(hw + l * HCOL);
        float tot = 0.0f;
#pragma unroll
        for (int k = 0; k < 32; ++k) {
            float2 a = row2[(k + l) & 31];
            tot += (a.x + a.y);
        }
        hval = __fmul_rn(tot, 1.0f / 1024.0f);   // exact power-of-2 scale
    }

    // ---- Smoothing via lane shuffles (zero pad; lane 36 holds 0)
    float hm = __shfl_up(hval, 1, 64);
    if (l == 0) hm = 0.0f;
    float hp = __shfl_down(hval, 1, 64);
    float sm = 0.0f;
    if (l < NB) {
        sm = __fadd_rn(__fadd_rn(__fmul_rn(0.33f, hm), __fmul_rn(0.34f, hval)),
                       __fmul_rn(0.33f, hp));
    }

    // ---- First-wins argmax via packed-key butterfly (sm >= 0 always)
    unsigned long long key =
        (l < NB) ? ((((unsigned long long)__float_as_uint(sm)) << 6) |
                    (unsigned long long)(63 - l))
                 : 0ull;
#pragma unroll
    for (int off = 32; off > 0; off >>= 1) {
        unsigned long long o = __shfl_xor(key, off, 64);
        key = (o > key) ? o : key;
    }

    if (l == 0) {
        int bi = 63 - (int)(key & 63);
        float t2 = __fdiv_rn(__fmul_rn(TWOPI_F, (float)bi), 36.0f);
        out[patch] = __fsub_rn(PI_F, t2);
    }
}

extern "C" void kernel_launch(void* const* d_in, const int* in_sizes, int n_in,
                              void* d_out, int out_size, void* d_ws, size_t ws_size,
                              hipStream_t stream) {
    const float* x = (const float*)d_in[0];
    float* out = (float*)d_out;
    float* gk10 = (float*)d_ws;   // 1024 floats = 4 KB scratch

    const int B = in_sizes[0] / NPIX;

    gk_init_kernel<<<1, 256, 0, stream>>>(gk10);
    orient_kernel<<<B / WPB, 256, 0, stream>>>(x, gk10, out);
}